// Round 1
// baseline (486.116 us; speedup 1.0000x reference)
//
#include <hip/hip_runtime.h>
#include <hip/hip_bf16.h>
#include <stdint.h>

// Problem: B=8192 rows, K=4*N=8192, N_out=2048.
// out[b, n] = sum_k weight[b, permuted k] * fc_w[n, k] + fc_b[n]
// Strategy: pass 1 applies the per-row 4-block permutation while converting
// fp32->bf16 into d_ws; pass 2 converts fc_w; pass 3 is an m97-structure
// bf16 MFMA GEMM (128x128 tile, BK=64, global_load_lds w=16) with fused bias.

using f32x4   = __attribute__((ext_vector_type(4))) float;
using bf16x8  = __attribute__((ext_vector_type(8))) __bf16;
using ushort8 = __attribute__((ext_vector_type(8))) unsigned short;

#define B_ROWS 8192
#define K_TOT  8192
#define N_OUT  2048

__device__ __forceinline__ unsigned short f2bf(float f) {
  union { float f; unsigned int u; } v;
  v.f = f;
  unsigned int r = v.u + 0x7FFFu + ((v.u >> 16) & 1u);  // RNE
  return (unsigned short)(r >> 16);
}

// perm[r] for output block r given swap flags (sequential swaps (1,2) then (2,3))
__device__ __forceinline__ int perm_src(int r, int s1, int s2) {
  int mid = s1 ? 1 : 2;
  return (r == 0) ? 0
       : (r == 1) ? (s1 ? 2 : 1)
       : (r == 2) ? (s2 ? 3 : mid)
                  : (s2 ? mid : 3);
}

// -------- pass 1: permute + convert weight [8192][8192] fp32 -> bf16 --------
// grid = B*4 blocks of 256 threads; each block does one (row, out-block) pair.
__global__ __launch_bounds__(256) void k_permute_convert(
    const float* __restrict__ w, const int* __restrict__ s1v,
    const int* __restrict__ s2v, unsigned short* __restrict__ xbf) {
  const int blk = blockIdx.x;
  const int b = blk >> 2, r = blk & 3;
  const int s1 = s1v[b] != 0, s2 = s2v[b] != 0;
  const int pr = perm_src(r, s1, s2);
  const float* src = w + (size_t)b * K_TOT + (size_t)pr * 2048 + threadIdx.x * 8;
  unsigned short* dst = xbf + (size_t)b * K_TOT + (size_t)r * 2048 + threadIdx.x * 8;
  f32x4 v0 = *(const f32x4*)src;
  f32x4 v1 = *(const f32x4*)(src + 4);
  ushort8 o;
#pragma unroll
  for (int j = 0; j < 4; ++j) o[j] = f2bf(v0[j]);
#pragma unroll
  for (int j = 0; j < 4; ++j) o[4 + j] = f2bf(v1[j]);
  *(ushort8*)dst = o;
}

// -------- pass 2: convert fc_w [2048][8192] fp32 -> bf16 --------
__global__ __launch_bounds__(256) void k_convert_w(
    const float* __restrict__ fw, unsigned short* __restrict__ wbf) {
  const size_t base = ((size_t)blockIdx.x * 256 + threadIdx.x) * 8;
  f32x4 v0 = *(const f32x4*)(fw + base);
  f32x4 v1 = *(const f32x4*)(fw + base + 4);
  ushort8 o;
#pragma unroll
  for (int j = 0; j < 4; ++j) o[j] = f2bf(v0[j]);
#pragma unroll
  for (int j = 0; j < 4; ++j) o[4 + j] = f2bf(v1[j]);
  *(ushort8*)(wbf + base) = o;
}

// -------- pass 3: bf16 GEMM, m97 structure --------
#define BM 128
#define BN 128
#define BK 64

__device__ __forceinline__ void gload16(const unsigned short* g,
                                        const unsigned short* l) {
  // linear LDS dest (wave-uniform base + lane*16), per-lane global src
  __builtin_amdgcn_global_load_lds(
      (__attribute__((address_space(1))) void*)(uintptr_t)(const void*)g,
      (__attribute__((address_space(3))) void*)(unsigned int)(uintptr_t)(const void*)l,
      16, 0, 0);
}

__global__ __launch_bounds__(256) void k_gemm(
    const unsigned short* __restrict__ A,   // [8192][8192] bf16 (permuted)
    const unsigned short* __restrict__ Bw,  // [2048][8192] bf16
    const float* __restrict__ bias,         // [2048]
    float* __restrict__ C) {                // [8192][2048] fp32
  __shared__ unsigned short lA[BM * BK];
  __shared__ unsigned short lB[BN * BK];
  const int tid  = threadIdx.x;
  const int lane = tid & 63;
  const int wave = tid >> 6;
  const int wr = wave >> 1, wc = wave & 1;
  const int bm = blockIdx.x & 63;   // 8192/128 = 64 M-tiles (fast dim: share B panel)
  const int bn = blockIdx.x >> 6;   // 2048/128 = 16 N-tiles

  const size_t a_row0 = (size_t)bm * BM;
  const size_t b_row0 = (size_t)bn * BN;

  f32x4 acc[4][4];
#pragma unroll
  for (int m = 0; m < 4; ++m)
#pragma unroll
    for (int n = 0; n < 4; ++n) {
      acc[m][n][0] = 0.f; acc[m][n][1] = 0.f; acc[m][n][2] = 0.f; acc[m][n][3] = 0.f;
    }

  for (int k0 = 0; k0 < K_TOT; k0 += BK) {
    // stage A tile [128][64] and B tile [128][64], 16B per lane
#pragma unroll
    for (int i = 0; i < 4; ++i) {
      int ci = i * 256 + tid;            // chunk index 0..1023
      int row = ci >> 3, cc = ci & 7;    // 8 x 16B chunks per 64-elem row
      gload16(A + (a_row0 + row) * (size_t)K_TOT + k0 + cc * 8, &lA[ci * 8]);
    }
#pragma unroll
    for (int i = 0; i < 4; ++i) {
      int ci = i * 256 + tid;
      int row = ci >> 3, cc = ci & 7;
      gload16(Bw + (b_row0 + row) * (size_t)K_TOT + k0 + cc * 8, &lB[ci * 8]);
    }
    __syncthreads();  // drains vmcnt before barrier -> tile visible

#pragma unroll
    for (int kk = 0; kk < 2; ++kk) {
      const int kcol = kk * 32 + (lane >> 4) * 8;
      bf16x8 af[4], bfr[4];
#pragma unroll
      for (int m = 0; m < 4; ++m)
        af[m] = *(const bf16x8*)&lA[(wr * 64 + m * 16 + (lane & 15)) * BK + kcol];
#pragma unroll
      for (int n = 0; n < 4; ++n)
        bfr[n] = *(const bf16x8*)&lB[(wc * 64 + n * 16 + (lane & 15)) * BK + kcol];
#pragma unroll
      for (int m = 0; m < 4; ++m)
#pragma unroll
        for (int n = 0; n < 4; ++n)
          acc[m][n] = __builtin_amdgcn_mfma_f32_16x16x32_bf16(af[m], bfr[n],
                                                              acc[m][n], 0, 0, 0);
    }
    __syncthreads();  // all waves done reading before next stage
  }

  // epilogue: C/D layout col = lane&15, row = (lane>>4)*4 + j  [m89-verified]
  const int row0 = bm * BM + wr * 64 + ((lane >> 4) << 2);
  const int col0 = bn * BN + wc * 64 + (lane & 15);
  float bv[4];
#pragma unroll
  for (int n = 0; n < 4; ++n) bv[n] = bias[col0 + n * 16];
#pragma unroll
  for (int m = 0; m < 4; ++m)
#pragma unroll
    for (int n = 0; n < 4; ++n) {
      const int r = row0 + m * 16;
      const int c = col0 + n * 16;
#pragma unroll
      for (int j = 0; j < 4; ++j)
        C[(size_t)(r + j) * N_OUT + c] = acc[m][n][j] + bv[n];
    }
}

// -------- fallback: fp32 tiled GEMM with inline permutation (ws too small) ----
__global__ __launch_bounds__(256) void k_gemm_fallback(
    const float* __restrict__ W, const float* __restrict__ FW,
    const float* __restrict__ bias, const int* __restrict__ s1v,
    const int* __restrict__ s2v, float* __restrict__ C) {
  __shared__ float As[64][33];
  __shared__ float Bs[64][33];
  const int tid = threadIdx.x;
  const int tx = tid & 15, ty = tid >> 4;
  const int bm = blockIdx.x & 127;  // 8192/64
  const int bn = blockIdx.x >> 7;   // 2048/64
  float acc[4][4] = {{0.f}};
  for (int k0 = 0; k0 < K_TOT; k0 += 32) {
#pragma unroll
    for (int i = 0; i < 8; ++i) {
      int idx = i * 256 + tid;  // 0..2047
      int rr = idx >> 5, cc = idx & 31;
      int grow = bm * 64 + rr;
      int gk = k0 + cc;
      int blkr = gk >> 11, within = gk & 2047;
      int s1 = s1v[grow] != 0, s2 = s2v[grow] != 0;
      int pr = perm_src(blkr, s1, s2);
      As[rr][cc] = W[(size_t)grow * K_TOT + (size_t)pr * 2048 + within];
      Bs[rr][cc] = FW[(size_t)(bn * 64 + rr) * K_TOT + gk];
    }
    __syncthreads();
#pragma unroll 8
    for (int kk = 0; kk < 32; ++kk) {
      float a[4], b[4];
#pragma unroll
      for (int i = 0; i < 4; ++i) a[i] = As[ty * 4 + i][kk];
#pragma unroll
      for (int j = 0; j < 4; ++j) b[j] = Bs[tx * 4 + j][kk];
#pragma unroll
      for (int i = 0; i < 4; ++i)
#pragma unroll
        for (int j = 0; j < 4; ++j) acc[i][j] += a[i] * b[j];
    }
    __syncthreads();
  }
#pragma unroll
  for (int i = 0; i < 4; ++i)
#pragma unroll
    for (int j = 0; j < 4; ++j) {
      int r = bm * 64 + ty * 4 + i, c = bn * 64 + tx * 4 + j;
      C[(size_t)r * N_OUT + c] = acc[i][j] + bias[c];
    }
}

extern "C" void kernel_launch(void* const* d_in, const int* in_sizes, int n_in,
                              void* d_out, int out_size, void* d_ws, size_t ws_size,
                              hipStream_t stream) {
  const float* weight = (const float*)d_in[0];  // [8192][8192]
  const float* fc_w   = (const float*)d_in[1];  // [2048][8192]
  const float* fc_b   = (const float*)d_in[2];  // [2048]
  const int*   swap1  = (const int*)d_in[3];    // [8192]
  const int*   swap2  = (const int*)d_in[4];    // [8192]
  float* out = (float*)d_out;

  const size_t xbf_bytes = (size_t)B_ROWS * K_TOT * 2;  // 128 MB
  const size_t wbf_bytes = (size_t)N_OUT * K_TOT * 2;   //  32 MB
  if (ws_size >= xbf_bytes + wbf_bytes) {
    unsigned short* xbf = (unsigned short*)d_ws;
    unsigned short* wbf = (unsigned short*)((char*)d_ws + xbf_bytes);
    k_permute_convert<<<B_ROWS * 4, 256, 0, stream>>>(weight, swap1, swap2, xbf);
    k_convert_w<<<(N_OUT * K_TOT) / 2048, 256, 0, stream>>>(fc_w, wbf);
    k_gemm<<<64 * 16, 256, 0, stream>>>(xbf, wbf, fc_b, out);
  } else {
    k_gemm_fallback<<<128 * 32, 256, 0, stream>>>(weight, fc_w, fc_b, swap1,
                                                  swap2, out);
  }
}

// Round 2
// 295.670 us; speedup vs baseline: 1.6441x; 1.6441x over previous
//
#include <hip/hip_runtime.h>
#include <hip/hip_bf16.h>
#include <stdint.h>

// out[b, n] = sum_k weight[b, perm(k)] * fc_w[n, k] + fc_b[n]
// Pass 1/2: fold permutation + fp32->bf16 into d_ws. Pass 3: 256^2 8-phase
// bf16 MFMA GEMM (T1 XCD mapping, T2 slot-XOR swizzle, T3/T4 counted vmcnt,
// T5 setprio), fused bias epilogue.

using f32x4   = __attribute__((ext_vector_type(4))) float;
using bf16x8  = __attribute__((ext_vector_type(8))) __bf16;
using ushort8 = __attribute__((ext_vector_type(8))) unsigned short;

#define B_ROWS 8192
#define K_TOT  8192
#define N_OUT  2048
#define BK     64
#define NT     (K_TOT / BK)  // 128 K-tiles

__device__ __forceinline__ unsigned short f2bf(float f) {
  union { float f; unsigned int u; } v;
  v.f = f;
  unsigned int r = v.u + 0x7FFFu + ((v.u >> 16) & 1u);  // RNE
  return (unsigned short)(r >> 16);
}

__device__ __forceinline__ int perm_src(int r, int s1, int s2) {
  int mid = s1 ? 1 : 2;
  return (r == 0) ? 0
       : (r == 1) ? (s1 ? 2 : 1)
       : (r == 2) ? (s2 ? 3 : mid)
                  : (s2 ? mid : 3);
}

// -------- pass 1: permute + convert weight [8192][8192] fp32 -> bf16 --------
__global__ __launch_bounds__(256) void k_permute_convert(
    const float* __restrict__ w, const int* __restrict__ s1v,
    const int* __restrict__ s2v, unsigned short* __restrict__ xbf) {
  const int blk = blockIdx.x;
  const int b = blk >> 2, r = blk & 3;
  const int s1 = s1v[b] != 0, s2 = s2v[b] != 0;
  const int pr = perm_src(r, s1, s2);
  const float* src = w + (size_t)b * K_TOT + (size_t)pr * 2048 + threadIdx.x * 8;
  unsigned short* dst = xbf + (size_t)b * K_TOT + (size_t)r * 2048 + threadIdx.x * 8;
  f32x4 v0 = *(const f32x4*)src;
  f32x4 v1 = *(const f32x4*)(src + 4);
  ushort8 o;
#pragma unroll
  for (int j = 0; j < 4; ++j) o[j] = f2bf(v0[j]);
#pragma unroll
  for (int j = 0; j < 4; ++j) o[4 + j] = f2bf(v1[j]);
  *(ushort8*)dst = o;
}

// -------- pass 2: convert fc_w [2048][8192] fp32 -> bf16 --------
__global__ __launch_bounds__(256) void k_convert_w(
    const float* __restrict__ fw, unsigned short* __restrict__ wbf) {
  const size_t base = ((size_t)blockIdx.x * 256 + threadIdx.x) * 8;
  f32x4 v0 = *(const f32x4*)(fw + base);
  f32x4 v1 = *(const f32x4*)(fw + base + 4);
  ushort8 o;
#pragma unroll
  for (int j = 0; j < 4; ++j) o[j] = f2bf(v0[j]);
#pragma unroll
  for (int j = 0; j < 4; ++j) o[4 + j] = f2bf(v1[j]);
  *(ushort8*)(wbf + base) = o;
}

// -------- pass 3: 256x256-tile 8-phase bf16 GEMM --------
__device__ __forceinline__ void gload16(const unsigned short* g,
                                        const unsigned short* l) {
  __builtin_amdgcn_global_load_lds(
      (__attribute__((address_space(1))) void*)(uintptr_t)(const void*)g,
      (__attribute__((address_space(3))) void*)(unsigned int)(uintptr_t)(const void*)l,
      16, 0, 0);
}

// LDS: sm[buf(2)][ A:16384 | B:16384 ] ushorts = 128 KiB total.
// Tile layout per operand: [256 rows][64 cols] bf16, 128 B/row = 8 x 16B slots.
// Swizzle: 16B slot s of row r holds global slot (s ^ (r&7)) — involution,
// applied on the global SOURCE address at staging and on ds_read addresses.

#define VMW4 asm volatile("s_waitcnt vmcnt(4)" ::: "memory")
#define VMW0 asm volatile("s_waitcnt vmcnt(0)" ::: "memory")
#define VMWN ((void)0)
#define LGKM0_FENCE do { \
    asm volatile("s_waitcnt lgkmcnt(0)" ::: "memory"); \
    __builtin_amdgcn_sched_barrier(0); } while (0)

#define LDA(BU, MH, M, KKI) \
  (*(const bf16x8*)(smb + (BU)*65536 + aBase + ((MH)*64 + (M)*16)*128 + colsw[KKI]))
#define LDB(BU, NH, N, KKI) \
  (*(const bf16x8*)(smb + (BU)*65536 + 32768 + bBase + ((NH)*32 + (N)*16)*128 + colsw[KKI]))

// one half-tile (128 rows x 64 cols) = 2 global_load_lds x 512 threads
#define STAGE(BU, OPL, GOP, H, T) do { \
  gload16((GOP) + (size_t)((H)*128 + row0) * K_TOT + (size_t)(T)*BK + sl0, \
          smu + (BU)*32768 + (OPL) + (H)*8192 + tid*8); \
  gload16((GOP) + (size_t)((H)*128 + row1) * K_TOT + (size_t)(T)*BK + sl1, \
          smu + (BU)*32768 + (OPL) + (H)*8192 + 4096 + tid*8); \
} while (0)

#define QUAD(MH, NH, B0A, B1A) do { \
  _Pragma("unroll") for (int m_ = 0; m_ < 4; ++m_) \
    _Pragma("unroll") for (int n_ = 0; n_ < 2; ++n_) { \
      acc[(MH)*4+m_][(NH)*2+n_] = __builtin_amdgcn_mfma_f32_16x16x32_bf16( \
          aR0[m_], B0A[n_], acc[(MH)*4+m_][(NH)*2+n_], 0, 0, 0); \
      acc[(MH)*4+m_][(NH)*2+n_] = __builtin_amdgcn_mfma_f32_16x16x32_bf16( \
          aR1[m_], B1A[n_], acc[(MH)*4+m_][(NH)*2+n_], 0, 0, 0); \
    } \
} while (0)

// Per K-tile: 4 phases. Staging plan (verified against read schedule):
//  P1: ds A-lo(8)+B-lo(4);  stage A0(t+1) -> other buf
//  P2: ds B-hi(4);          stage A1(t+1) -> other buf
//  P3: ds A-hi(8);          stage B0(t+2) -> CURRENT buf (B reads done @P2)
//  P4: no ds;               stage B1(t+2) -> CURRENT buf; counted vmcnt
#define TILE(BU, T, DOA, DOB, WAIT) do { \
  _Pragma("unroll") for (int m_ = 0; m_ < 4; ++m_) { \
    aR0[m_] = LDA(BU, 0, m_, 0); aR1[m_] = LDA(BU, 0, m_, 1); } \
  _Pragma("unroll") for (int n_ = 0; n_ < 2; ++n_) { \
    bL0[n_] = LDB(BU, 0, n_, 0); bL1[n_] = LDB(BU, 0, n_, 1); } \
  if (DOA) STAGE((BU) ^ 1, 0, gA, 0, (T) + 1); \
  __builtin_amdgcn_s_barrier(); \
  LGKM0_FENCE; \
  __builtin_amdgcn_s_setprio(1); QUAD(0, 0, bL0, bL1); __builtin_amdgcn_s_setprio(0); \
  __builtin_amdgcn_s_barrier(); \
  _Pragma("unroll") for (int n_ = 0; n_ < 2; ++n_) { \
    bH0[n_] = LDB(BU, 1, n_, 0); bH1[n_] = LDB(BU, 1, n_, 1); } \
  if (DOA) STAGE((BU) ^ 1, 0, gA, 1, (T) + 1); \
  __builtin_amdgcn_s_barrier(); \
  LGKM0_FENCE; \
  __builtin_amdgcn_s_setprio(1); QUAD(0, 1, bH0, bH1); __builtin_amdgcn_s_setprio(0); \
  __builtin_amdgcn_s_barrier(); \
  _Pragma("unroll") for (int m_ = 0; m_ < 4; ++m_) { \
    aR0[m_] = LDA(BU, 1, m_, 0); aR1[m_] = LDA(BU, 1, m_, 1); } \
  if (DOB) STAGE(BU, 16384, gB, 0, (T) + 2); \
  __builtin_amdgcn_s_barrier(); \
  LGKM0_FENCE; \
  __builtin_amdgcn_s_setprio(1); QUAD(1, 0, bL0, bL1); __builtin_amdgcn_s_setprio(0); \
  __builtin_amdgcn_s_barrier(); \
  if (DOB) STAGE(BU, 16384, gB, 1, (T) + 2); \
  __builtin_amdgcn_s_barrier(); \
  __builtin_amdgcn_s_setprio(1); QUAD(1, 1, bH0, bH1); __builtin_amdgcn_s_setprio(0); \
  WAIT; \
  __builtin_amdgcn_s_barrier(); \
} while (0)

__global__ __launch_bounds__(512, 2) void k_gemm8(
    const unsigned short* __restrict__ A,   // [8192][8192] bf16 (permuted)
    const unsigned short* __restrict__ Bw,  // [2048][8192] bf16
    const float* __restrict__ bias,         // [2048]
    float* __restrict__ C) {                // [8192][2048] fp32
  __shared__ unsigned short sm[2 * 32768];  // 128 KiB
  unsigned short* smu = sm;
  const char* smb = (const char*)sm;

  const int tid  = threadIdx.x;
  const int lane = tid & 63;
  const int wave = tid >> 6;
  const int wr = wave >> 2;              // 0..1 -> 128-row half
  const int wc = wave & 3;               // 0..3 -> 64-col slice
  const int bn = blockIdx.x & 7;         // XCD k owns B-panel column k (T1)
  const int bm = blockIdx.x >> 3;        // 0..31

  const unsigned short* gA = A  + (size_t)bm * 256 * K_TOT;
  const unsigned short* gB = Bw + (size_t)bn * 256 * K_TOT;

  // staging address precompute (chunk ci = round*512 + tid; 8 slots/row)
  const int row0 = tid >> 3;
  const int sl0  = (((tid & 7) ^ (row0 & 7)) << 3);  // element offset of 16B slot
  const int row1 = (512 + tid) >> 3;
  const int sl1  = ((((512 + tid) & 7) ^ (row1 & 7)) << 3);

  // ds_read address precompute: byte col = (kk*64 | hi16*16) ^ ((lane&7)<<4)
  const int l15 = lane & 15;
  int colsw[2];
  colsw[0] = (((lane >> 4) << 4)) ^ ((lane & 7) << 4);
  colsw[1] = (64 | ((lane >> 4) << 4)) ^ ((lane & 7) << 4);
  const int aBase = (wr * 128 + l15) * 128;
  const int bBase = (wc * 64 + l15) * 128;

  f32x4 acc[8][4];
#pragma unroll
  for (int i = 0; i < 8; ++i)
#pragma unroll
    for (int j = 0; j < 4; ++j) {
      acc[i][j][0] = 0.f; acc[i][j][1] = 0.f; acc[i][j][2] = 0.f; acc[i][j][3] = 0.f;
    }
  bf16x8 aR0[4], aR1[4], bL0[2], bL1[2], bH0[2], bH1[2];

  // prologue: tile0 fully + B-halves of tile1; wait tile0 landed (vmcnt(4))
  STAGE(0, 0,     gA, 0, 0);
  STAGE(0, 0,     gA, 1, 0);
  STAGE(0, 16384, gB, 0, 0);
  STAGE(0, 16384, gB, 1, 0);
  STAGE(1, 16384, gB, 0, 1);
  STAGE(1, 16384, gB, 1, 1);
  VMW4;
  __builtin_amdgcn_s_barrier();

  int t = 0;
  for (; t < NT - 4; t += 2) {   // t = 0,2,...,122
    TILE(0, t,     true, true, VMW4);
    TILE(1, t + 1, true, true, VMW4);
  }
  TILE(0, 124, true,  true,  VMW4);
  TILE(1, 125, true,  true,  VMW4);
  TILE(0, 126, true,  false, VMW0);   // stages A(127) only; full drain
  TILE(1, 127, false, false, VMWN);   // last tile: no staging, no wait

  // epilogue: C/D layout col = lane&15, row = (lane>>4)*4 + j
  const int crow0 = bm * 256 + wr * 128 + ((lane >> 4) << 2);
  const int ccol0 = bn * 256 + wc * 64 + l15;
  float bv[4];
#pragma unroll
  for (int n = 0; n < 4; ++n) bv[n] = bias[ccol0 + n * 16];
#pragma unroll
  for (int mi = 0; mi < 8; ++mi)
#pragma unroll
    for (int ni = 0; ni < 4; ++ni) {
      const int r = crow0 + mi * 16;
      const int c = ccol0 + ni * 16;
#pragma unroll
      for (int j = 0; j < 4; ++j)
        C[(size_t)(r + j) * N_OUT + c] = acc[mi][ni][j] + bv[ni];
    }
}

// -------- fallback: fp32 tiled GEMM with inline permutation (ws too small) ----
__global__ __launch_bounds__(256) void k_gemm_fallback(
    const float* __restrict__ W, const float* __restrict__ FW,
    const float* __restrict__ bias, const int* __restrict__ s1v,
    const int* __restrict__ s2v, float* __restrict__ C) {
  __shared__ float As[64][33];
  __shared__ float Bs[64][33];
  const int tid = threadIdx.x;
  const int tx = tid & 15, ty = tid >> 4;
  const int bm = blockIdx.x & 127;
  const int bn = blockIdx.x >> 7;
  float acc[4][4] = {{0.f}};
  for (int k0 = 0; k0 < K_TOT; k0 += 32) {
#pragma unroll
    for (int i = 0; i < 8; ++i) {
      int idx = i * 256 + tid;
      int rr = idx >> 5, cc = idx & 31;
      int grow = bm * 64 + rr;
      int gk = k0 + cc;
      int blkr = gk >> 11, within = gk & 2047;
      int s1 = s1v[grow] != 0, s2 = s2v[grow] != 0;
      int pr = perm_src(blkr, s1, s2);
      As[rr][cc] = W[(size_t)grow * K_TOT + (size_t)pr * 2048 + within];
      Bs[rr][cc] = FW[(size_t)(bn * 64 + rr) * K_TOT + gk];
    }
    __syncthreads();
#pragma unroll 8
    for (int kk = 0; kk < 32; ++kk) {
      float a[4], b[4];
#pragma unroll
      for (int i = 0; i < 4; ++i) a[i] = As[ty * 4 + i][kk];
#pragma unroll
      for (int j = 0; j < 4; ++j) b[j] = Bs[tx * 4 + j][kk];
#pragma unroll
      for (int i = 0; i < 4; ++i)
#pragma unroll
        for (int j = 0; j < 4; ++j) acc[i][j] += a[i] * b[j];
    }
    __syncthreads();
  }
#pragma unroll
  for (int i = 0; i < 4; ++i)
#pragma unroll
    for (int j = 0; j < 4; ++j) {
      int r = bm * 64 + ty * 4 + i, c = bn * 64 + tx * 4 + j;
      C[(size_t)r * N_OUT + c] = acc[i][j] + bias[c];
    }
}

extern "C" void kernel_launch(void* const* d_in, const int* in_sizes, int n_in,
                              void* d_out, int out_size, void* d_ws, size_t ws_size,
                              hipStream_t stream) {
  const float* weight = (const float*)d_in[0];  // [8192][8192]
  const float* fc_w   = (const float*)d_in[1];  // [2048][8192]
  const float* fc_b   = (const float*)d_in[2];  // [2048]
  const int*   swap1  = (const int*)d_in[3];    // [8192]
  const int*   swap2  = (const int*)d_in[4];    // [8192]
  float* out = (float*)d_out;

  const size_t xbf_bytes = (size_t)B_ROWS * K_TOT * 2;  // 128 MB
  const size_t wbf_bytes = (size_t)N_OUT * K_TOT * 2;   //  32 MB
  if (ws_size >= xbf_bytes + wbf_bytes) {
    unsigned short* xbf = (unsigned short*)d_ws;
    unsigned short* wbf = (unsigned short*)((char*)d_ws + xbf_bytes);
    k_permute_convert<<<B_ROWS * 4, 256, 0, stream>>>(weight, swap1, swap2, xbf);
    k_convert_w<<<(N_OUT * K_TOT) / 2048, 256, 0, stream>>>(fc_w, wbf);
    k_gemm8<<<32 * 8, 512, 0, stream>>>(xbf, wbf, fc_b, out);
  } else {
    k_gemm_fallback<<<128 * 32, 256, 0, stream>>>(weight, fc_w, fc_b, swap1,
                                                  swap2, out);
  }
}